// Round 1
// baseline (216.230 us; speedup 1.0000x reference)
//
#include <hip/hip_runtime.h>
#include <hip/hip_bf16.h>
#include <stdint.h>

typedef __attribute__((ext_vector_type(8))) short short8;
typedef __attribute__((ext_vector_type(8))) __bf16 bf16x8;
typedef __attribute__((ext_vector_type(4))) float f32x4;

#define BATCH 8
#define NTOK 1024
#define CDIM 256
#define NHEADS 8
#define HD 32

__device__ __forceinline__ unsigned short f2bf(float f) {
  unsigned int u = __builtin_bit_cast(unsigned int, f);
  u += 0x7fffu + ((u >> 16) & 1u);
  return (unsigned short)(u >> 16);
}

__device__ __forceinline__ f32x4 mfma16(short8 a, short8 b, f32x4 c) {
  return __builtin_amdgcn_mfma_f32_16x16x32_bf16(
      __builtin_bit_cast(bf16x8, a), __builtin_bit_cast(bf16x8, b), c, 0, 0, 0);
}

__device__ __forceinline__ short8 ld8(const unsigned short* p) {
  return *reinterpret_cast<const short8*>(p);
}

// ---------------- weight fp32 -> bf16 ----------------
__global__ __launch_bounds__(256) void k_cvt(const float* __restrict__ wqkv,
                                             const float* __restrict__ wproj,
                                             unsigned short* __restrict__ wqkv_bf,
                                             unsigned short* __restrict__ wproj_bf) {
  int i = blockIdx.x * 256 + threadIdx.x;
  if (i < 768 * 256) wqkv_bf[i] = f2bf(wqkv[i]);
  if (i < 256 * 256) wproj_bf[i] = f2bf(wproj[i]);
}

// ---------------- wind strength (2x2 avg pool of magnitude) ----------------
__global__ __launch_bounds__(256) void k_wind(const float* __restrict__ u,
                                              const float* __restrict__ v,
                                              float* __restrict__ ws) {
  int i = blockIdx.x * 256 + threadIdx.x;  // [0, 8192)
  int b = i >> 10, n = i & 1023;
  int ph = n >> 5, pw = n & 31;
  const float* ub = u + b * 4096;
  const float* vb = v + b * 4096;
  float s = 0.f;
#pragma unroll
  for (int dy = 0; dy < 2; ++dy)
#pragma unroll
    for (int dx = 0; dx < 2; ++dx) {
      int idx = (2 * ph + dy) * 64 + (2 * pw + dx);
      float uu = ub[idx], vv = vb[idx];
      s += sqrtf(uu * uu + vv * vv + 1e-8f);
    }
  ws[i] = s * 0.25f;
}

// ---------------- QKV GEMM: x[8192,256] @ wqkv^T -> q/k/v bf16 [B,H,N,32] ----
__global__ __launch_bounds__(256) void k_qkv(const float* __restrict__ x,
                                             const unsigned short* __restrict__ wq_bf,
                                             unsigned short* __restrict__ qb,
                                             unsigned short* __restrict__ kb,
                                             unsigned short* __restrict__ vb) {
  const int lane = threadIdx.x & 63;
  const int w = threadIdx.x >> 6;  // wave 0..3
  const int c = lane & 15, g = lane >> 4;
  const int m0 = blockIdx.y * 64 + w * 16;
  const int n0 = blockIdx.x * 64;
  f32x4 acc[4] = {};
#pragma unroll
  for (int k0 = 0; k0 < 256; k0 += 32) {
    const float* xp = x + (size_t)(m0 + c) * 256 + k0 + g * 8;
    f32x4 a0 = *reinterpret_cast<const f32x4*>(xp);
    f32x4 a1 = *reinterpret_cast<const f32x4*>(xp + 4);
    short8 af;
#pragma unroll
    for (int j = 0; j < 4; ++j) {
      af[j] = (short)f2bf(a0[j]);
      af[4 + j] = (short)f2bf(a1[j]);
    }
#pragma unroll
    for (int nb = 0; nb < 4; ++nb) {
      short8 bf = ld8(wq_bf + (size_t)(n0 + nb * 16 + c) * 256 + k0 + g * 8);
      acc[nb] = mfma16(af, bf, acc[nb]);
    }
  }
#pragma unroll
  for (int nb = 0; nb < 4; ++nb) {
    int col = n0 + nb * 16 + c;  // [0,768)
    int s = col >> 8, rem = col & 255;
    int h = rem >> 5, d = rem & 31;
    unsigned short* dst = (s == 0) ? qb : ((s == 1) ? kb : vb);
    float scale = (s == 0) ? 0.17677669529663687f : 1.0f;  // hd^-0.5 folded into q
#pragma unroll
    for (int r = 0; r < 4; ++r) {
      int row = m0 + g * 4 + r;  // [0,8192)
      int b = row >> 10, nn = row & 1023;
      dst[((size_t)(b * 8 + h) * 1024 + nn) * 32 + d] = f2bf(acc[nb][r] * scale);
    }
  }
}

// ---------------- V transpose: [BH,1024,32] -> [BH,32,1024] ----------------
__global__ __launch_bounds__(256) void k_vtrans(const unsigned short* __restrict__ vb,
                                                unsigned short* __restrict__ vT) {
  __shared__ unsigned short tile[64][33];
  int bh = blockIdx.y;
  int n0 = blockIdx.x * 64;
  int t = threadIdx.x;
  const unsigned short* src = vb + (size_t)bh * 1024 * 32 + (size_t)n0 * 32;
  short8 vv = ld8(src + t * 8);
  int n = (t * 8) >> 5, d0 = (t * 8) & 31;
#pragma unroll
  for (int j = 0; j < 8; ++j) tile[n][d0 + j] = (unsigned short)vv[j];
  __syncthreads();
  unsigned short* dst = vT + (size_t)bh * 32 * 1024;
  int d = (t * 8) >> 6, nn0 = (t * 8) & 63;
  short8 o;
#pragma unroll
  for (int j = 0; j < 8; ++j) o[j] = (short)tile[nn0 + j][d];
  *reinterpret_cast<short8*>(dst + (size_t)d * 1024 + n0 + nn0) = o;
}

// ---------------- fused attention ----------------
// grid: (N/32, B), block 512 = 8 waves; wave w handles head h=w for q rows [q0, q0+32)
__global__ __launch_bounds__(512) void k_attn(const unsigned short* __restrict__ qb,
                                              const unsigned short* __restrict__ kb,
                                              const unsigned short* __restrict__ vT,
                                              const float* __restrict__ elev,
                                              const float* __restrict__ wsd,
                                              const float* __restrict__ alphap,
                                              const float* __restrict__ betap,
                                              float* __restrict__ ao) {
  __shared__ float bias_lds[32][65];
  __shared__ unsigned short p_lds[8][32][72];
  const int tid = threadIdx.x;
  const int w = tid >> 6, lane = tid & 63;
  const int c = lane & 15, g = lane >> 4;
  const int b = blockIdx.y, q0 = blockIdx.x * 32, h = w;
  const float alpha = alphap[0], beta = betap[0];
  const float* eb = elev + b * 1024;
  const float* wb = wsd + b * 1024;
  const size_t bh = (size_t)(b * 8 + h);

  short8 qf[2];
#pragma unroll
  for (int qs = 0; qs < 2; ++qs)
    qf[qs] = ld8(qb + (bh * 1024 + q0 + qs * 16 + c) * 32 + g * 8);

  f32x4 oacc[2][2] = {};
  float mrow[2][4], lrow[2][4];
#pragma unroll
  for (int qs = 0; qs < 2; ++qs)
#pragma unroll
    for (int r = 0; r < 4; ++r) { mrow[qs][r] = -1e30f; lrow[qs][r] = 0.f; }

  for (int kv0 = 0; kv0 < 1024; kv0 += 64) {
    __syncthreads();  // previous tile's bias reads complete
    // cooperative bias tile [32 q][64 kv], shared by all 8 heads
#pragma unroll
    for (int e = tid; e < 2048; e += 512) {
      int qr = e >> 6, kvl = e & 63;
      float ei = eb[q0 + qr], ej = eb[kv0 + kvl];
      float wi = wb[q0 + qr], wj = wb[kv0 + kvl];
      float dd = fmaxf((ej - ei) * 1e-3f, 0.f);
      float tm = (wi + wj) * 0.5f - 5.0f;
      float sig = 1.0f / (1.0f + __expf(-tm));
      float bias = -alpha * dd * (1.0f - beta * sig);
      bias_lds[qr][kvl] = fminf(fmaxf(bias, -10.0f), 0.0f);
    }
    __syncthreads();

    // S = Q K^T (scale folded into Q)
    short8 kf[4];
#pragma unroll
    for (int t = 0; t < 4; ++t)
      kf[t] = ld8(kb + (bh * 1024 + kv0 + t * 16 + c) * 32 + g * 8);
    f32x4 sa[2][4];
#pragma unroll
    for (int qs = 0; qs < 2; ++qs)
#pragma unroll
      for (int t = 0; t < 4; ++t) {
        f32x4 z = {};
        sa[qs][t] = mfma16(qf[qs], kf[t], z);
      }

    // online softmax (row = q, held by 16-lane groups; per-lane rows via (g,r))
#pragma unroll
    for (int qs = 0; qs < 2; ++qs) {
#pragma unroll
      for (int r = 0; r < 4; ++r) {
        int qr = qs * 16 + g * 4 + r;
        float mx = -1e30f;
#pragma unroll
        for (int t = 0; t < 4; ++t) {
          float sv = sa[qs][t][r] + bias_lds[qr][t * 16 + c];
          sa[qs][t][r] = sv;
          mx = fmaxf(mx, sv);
        }
#pragma unroll
        for (int mk = 1; mk < 16; mk <<= 1) mx = fmaxf(mx, __shfl_xor(mx, mk));
        float mo = mrow[qs][r];
        float mn = fmaxf(mo, mx);
        float corr = __expf(mo - mn);
        mrow[qs][r] = mn;
        float ps = 0.f;
#pragma unroll
        for (int t = 0; t < 4; ++t) {
          float p = __expf(sa[qs][t][r] - mn);
          sa[qs][t][r] = p;
          ps += p;
        }
#pragma unroll
        for (int mk = 1; mk < 16; mk <<= 1) ps += __shfl_xor(ps, mk);
        lrow[qs][r] = lrow[qs][r] * corr + ps;
        oacc[qs][0][r] *= corr;
        oacc[qs][1][r] *= corr;
#pragma unroll
        for (int t = 0; t < 4; ++t)
          p_lds[w][qr][t * 16 + c] = f2bf(sa[qs][t][r]);
      }
    }

    // O += P V  (A-frag of P from per-wave LDS; V fragments from transposed V)
#pragma unroll
    for (int t2 = 0; t2 < 2; ++t2) {
      short8 pa[2];
#pragma unroll
      for (int qs = 0; qs < 2; ++qs)
        pa[qs] = ld8(&p_lds[w][qs * 16 + c][t2 * 32 + g * 8]);
#pragma unroll
      for (int hs = 0; hs < 2; ++hs) {
        short8 vf = ld8(vT + (bh * 32 + hs * 16 + c) * 1024 + kv0 + t2 * 32 + g * 8);
#pragma unroll
        for (int qs = 0; qs < 2; ++qs)
          oacc[qs][hs] = mfma16(pa[qs], vf, oacc[qs][hs]);
      }
    }
  }

  // epilogue: normalize and write attn-out fp32 [B*N, 256]
#pragma unroll
  for (int qs = 0; qs < 2; ++qs)
#pragma unroll
    for (int hs = 0; hs < 2; ++hs)
#pragma unroll
      for (int r = 0; r < 4; ++r) {
        int qr = qs * 16 + g * 4 + r;
        float val = oacc[qs][hs][r] / lrow[qs][r];
        ao[(size_t)(b * 1024 + q0 + qr) * 256 + h * 32 + hs * 16 + c] = val;
      }
}

// ---------------- projection: ao[8192,256] @ wproj^T + b ----------------
__global__ __launch_bounds__(256) void k_proj(const float* __restrict__ ao,
                                              const unsigned short* __restrict__ wp_bf,
                                              const float* __restrict__ bproj,
                                              float* __restrict__ out) {
  const int lane = threadIdx.x & 63;
  const int w = threadIdx.x >> 6;
  const int c = lane & 15, g = lane >> 4;
  const int m0 = blockIdx.y * 64 + w * 16;
  const int n0 = blockIdx.x * 64;
  f32x4 acc[4] = {};
#pragma unroll
  for (int k0 = 0; k0 < 256; k0 += 32) {
    const float* ap = ao + (size_t)(m0 + c) * 256 + k0 + g * 8;
    f32x4 a0 = *reinterpret_cast<const f32x4*>(ap);
    f32x4 a1 = *reinterpret_cast<const f32x4*>(ap + 4);
    short8 af;
#pragma unroll
    for (int j = 0; j < 4; ++j) {
      af[j] = (short)f2bf(a0[j]);
      af[4 + j] = (short)f2bf(a1[j]);
    }
#pragma unroll
    for (int nb = 0; nb < 4; ++nb) {
      short8 bf = ld8(wp_bf + (size_t)(n0 + nb * 16 + c) * 256 + k0 + g * 8);
      acc[nb] = mfma16(af, bf, acc[nb]);
    }
  }
#pragma unroll
  for (int nb = 0; nb < 4; ++nb) {
    int col = n0 + nb * 16 + c;
    float bv = bproj[col];
#pragma unroll
    for (int r = 0; r < 4; ++r) {
      int row = m0 + g * 4 + r;
      out[(size_t)row * 256 + col] = acc[nb][r] + bv;
    }
  }
}

extern "C" void kernel_launch(void* const* d_in, const int* in_sizes, int n_in,
                              void* d_out, int out_size, void* d_ws, size_t ws_size,
                              hipStream_t stream) {
  const float* x = (const float*)d_in[0];
  const float* elev = (const float*)d_in[1];
  const float* uw = (const float*)d_in[2];
  const float* vw = (const float*)d_in[3];
  const float* wqkv = (const float*)d_in[4];
  const float* wproj = (const float*)d_in[5];
  const float* bproj = (const float*)d_in[6];
  const float* alpha = (const float*)d_in[7];
  const float* beta = (const float*)d_in[8];
  float* out = (float*)d_out;

  char* p = (char*)d_ws;
  auto alloc = [&](size_t bytes) {
    char* r = p;
    p += (bytes + 255) & ~(size_t)255;
    return r;
  };
  float* ws_wind = (float*)alloc(8192 * 4);
  unsigned short* wqkv_bf = (unsigned short*)alloc((size_t)768 * 256 * 2);
  unsigned short* wproj_bf = (unsigned short*)alloc((size_t)256 * 256 * 2);
  unsigned short* qb = (unsigned short*)alloc((size_t)2097152 * 2);
  unsigned short* kb = (unsigned short*)alloc((size_t)2097152 * 2);
  unsigned short* vb = (unsigned short*)alloc((size_t)2097152 * 2);
  unsigned short* vT = (unsigned short*)alloc((size_t)2097152 * 2);
  float* ao = (float*)alloc((size_t)2097152 * 4);

  k_cvt<<<dim3(768), dim3(256), 0, stream>>>(wqkv, wproj, wqkv_bf, wproj_bf);
  k_wind<<<dim3(32), dim3(256), 0, stream>>>(uw, vw, ws_wind);
  k_qkv<<<dim3(12, 128), dim3(256), 0, stream>>>(x, wqkv_bf, qb, kb, vb);
  k_vtrans<<<dim3(16, 64), dim3(256), 0, stream>>>(vb, vT);
  k_attn<<<dim3(32, 8), dim3(512), 0, stream>>>(qb, kb, vT, elev, ws_wind, alpha, beta, ao);
  k_proj<<<dim3(4, 128), dim3(256), 0, stream>>>(ao, wproj_bf, bproj, out);
}

// Round 2
// 169.176 us; speedup vs baseline: 1.2781x; 1.2781x over previous
//
#include <hip/hip_runtime.h>
#include <stdint.h>

typedef __attribute__((ext_vector_type(8))) short short8;
typedef __attribute__((ext_vector_type(8))) __bf16 bf16x8;
typedef __attribute__((ext_vector_type(4))) float f32x4;
typedef __attribute__((ext_vector_type(4))) _Float16 f16x4;
typedef __attribute__((ext_vector_type(4))) unsigned short ushort4_t;
typedef __attribute__((ext_vector_type(4))) unsigned int uint4_t;
typedef __attribute__((ext_vector_type(2))) unsigned int uint2_t;
typedef __attribute__((ext_vector_type(2))) float float2_t;

__device__ __forceinline__ unsigned short f2bf(float f) {
  unsigned int u = __builtin_bit_cast(unsigned int, f);
  u += 0x7fffu + ((u >> 16) & 1u);
  return (unsigned short)(u >> 16);
}

__device__ __forceinline__ f32x4 mfma16(short8 a, short8 b, f32x4 c) {
  return __builtin_amdgcn_mfma_f32_16x16x32_bf16(
      __builtin_bit_cast(bf16x8, a), __builtin_bit_cast(bf16x8, b), c, 0, 0, 0);
}

__device__ __forceinline__ short8 ld8(const unsigned short* p) {
  return *reinterpret_cast<const short8*>(p);
}

// ---------------- prep: weight cvt + wind strength ----------------
__global__ __launch_bounds__(256) void k_prep(const float* __restrict__ wqkv,
                                              const float* __restrict__ wproj,
                                              const float* __restrict__ u,
                                              const float* __restrict__ v,
                                              unsigned short* __restrict__ wqkv_bf,
                                              unsigned short* __restrict__ wproj_bf,
                                              float* __restrict__ ws) {
  int gx = blockIdx.x, t = threadIdx.x;
  if (gx < 768) {
    int i = gx * 256 + t;
    wqkv_bf[i] = f2bf(wqkv[i]);
  } else if (gx < 1024) {
    int i = (gx - 768) * 256 + t;
    wproj_bf[i] = f2bf(wproj[i]);
  } else {
    int i = (gx - 1024) * 256 + t;  // [0, 8192)
    int b = i >> 10, n = i & 1023;
    int ph = n >> 5, pw = n & 31;
    const float* ub = u + b * 4096;
    const float* vb = v + b * 4096;
    float s = 0.f;
#pragma unroll
    for (int dy = 0; dy < 2; ++dy)
#pragma unroll
      for (int dx = 0; dx < 2; ++dx) {
        int idx = (2 * ph + dy) * 64 + (2 * pw + dx);
        float uu = ub[idx], vv = vb[idx];
        s += sqrtf(uu * uu + vv * vv + 1e-8f);
      }
    ws[i] = s * 0.25f;
  }
}

// ---------------- bias precompute: [B,1024,1024] fp16 ----------------
__global__ __launch_bounds__(256) void k_bias(const float* __restrict__ elev,
                                              const float* __restrict__ ws,
                                              const float* __restrict__ alphap,
                                              const float* __restrict__ betap,
                                              _Float16* __restrict__ bias16) {
  const int i = blockIdx.x, b = blockIdx.y, t = threadIdx.x;
  const float alpha = alphap[0], beta = betap[0];
  const float ei = elev[b * 1024 + i];
  const float wi = ws[b * 1024 + i];
  const int j0 = t * 4;
  f32x4 ej = *reinterpret_cast<const f32x4*>(elev + b * 1024 + j0);
  f32x4 wj = *reinterpret_cast<const f32x4*>(ws + b * 1024 + j0);
  f16x4 h;
#pragma unroll
  for (int r = 0; r < 4; ++r) {
    float dd = fmaxf((ej[r] - ei) * 1e-3f, 0.f);
    float tm = (wi + wj[r]) * 0.5f - 5.0f;
    float sig = 1.0f / (1.0f + __expf(-tm));
    float bias = -alpha * dd * (1.0f - beta * sig);
    h[r] = (_Float16)fminf(fmaxf(bias, -10.0f), 0.0f);
  }
  *reinterpret_cast<f16x4*>(bias16 + ((size_t)(b * 1024 + i)) * 1024 + j0) = h;
}

// ---------------- QKV GEMM (LDS-staged A): x[8192,256] @ wqkv^T ----------------
__global__ __launch_bounds__(256, 4) void k_qkv(const float* __restrict__ x,
                                                const unsigned short* __restrict__ wq_bf,
                                                unsigned short* __restrict__ qb,
                                                unsigned short* __restrict__ kb,
                                                unsigned short* __restrict__ vb) {
  __shared__ unsigned short xs[64][264];
  const int tid = threadIdx.x;
  const int w = tid >> 6, lane = tid & 63;
  const int c = lane & 15, g = lane >> 4;
  const int m0 = blockIdx.y * 64;
  const int n0 = blockIdx.x * 64;
  // cooperative coalesced load + convert
#pragma unroll
  for (int i = 0; i < 16; ++i) {
    int idx = i * 1024 + tid * 4;
    int row = idx >> 8, col = idx & 255;
    f32x4 vv = *reinterpret_cast<const f32x4*>(x + (size_t)(m0 + row) * 256 + col);
    ushort4_t h;
#pragma unroll
    for (int j = 0; j < 4; ++j) h[j] = f2bf(vv[j]);
    *reinterpret_cast<ushort4_t*>(&xs[row][col]) = h;
  }
  __syncthreads();
  f32x4 acc[4] = {};
#pragma unroll
  for (int k0 = 0; k0 < 256; k0 += 32) {
    short8 af = ld8(&xs[w * 16 + c][k0 + g * 8]);
#pragma unroll
    for (int nb = 0; nb < 4; ++nb) {
      short8 bf = ld8(wq_bf + (size_t)(n0 + nb * 16 + c) * 256 + k0 + g * 8);
      acc[nb] = mfma16(af, bf, acc[nb]);
    }
  }
#pragma unroll
  for (int nb = 0; nb < 4; ++nb) {
    int col = n0 + nb * 16 + c;  // [0,768)
    int s = col >> 8, rem = col & 255;
    int h = rem >> 5, d = rem & 31;
    unsigned short* dst = (s == 0) ? qb : ((s == 1) ? kb : vb);
    float scale = (s == 0) ? 0.17677669529663687f : 1.0f;  // hd^-0.5 folded into q
#pragma unroll
    for (int r = 0; r < 4; ++r) {
      int row = m0 + w * 16 + g * 4 + r;  // [0,8192)
      int b = row >> 10, nn = row & 1023;
      dst[((size_t)(b * 8 + h) * 1024 + nn) * 32 + d] = f2bf(acc[nb][r] * scale);
    }
  }
}

// ---------------- V transpose: [BH,1024,32] -> [BH,32,1024] ----------------
__global__ __launch_bounds__(256) void k_vtrans(const unsigned short* __restrict__ vb,
                                                unsigned short* __restrict__ vT) {
  __shared__ unsigned short tile[64][33];
  int bh = blockIdx.y;
  int n0 = blockIdx.x * 64;
  int t = threadIdx.x;
  const unsigned short* src = vb + (size_t)bh * 1024 * 32 + (size_t)n0 * 32;
  short8 vv = ld8(src + t * 8);
  int n = (t * 8) >> 5, d0 = (t * 8) & 31;
#pragma unroll
  for (int j = 0; j < 8; ++j) tile[n][d0 + j] = (unsigned short)vv[j];
  __syncthreads();
  unsigned short* dst = vT + (size_t)bh * 32 * 1024;
  int d = (t * 8) >> 6, nn0 = (t * 8) & 63;
  short8 o;
#pragma unroll
  for (int j = 0; j < 8; ++j) o[j] = (short)tile[nn0 + j][d];
  *reinterpret_cast<short8*>(dst + (size_t)d * 1024 + n0 + nn0) = o;
}

// ---------------- fused attention, swapped-QK^T, kv-split ----------------
// grid: (32 qtiles, 8 b, 4 = hg + 2*split); block 256 = 4 waves; wave = head hg*4+w
__global__ __launch_bounds__(256, 4) void k_attn(const unsigned short* __restrict__ qb,
                                                 const unsigned short* __restrict__ kb,
                                                 const unsigned short* __restrict__ vT,
                                                 const _Float16* __restrict__ bias16,
                                                 float* __restrict__ o_part,
                                                 float* __restrict__ ml_part) {
  __shared__ _Float16 bias_lds[2][32][72];
  __shared__ unsigned short p_lds[4][32][72];
  const int tid = threadIdx.x;
  const int w = tid >> 6, lane = tid & 63;
  const int c = lane & 15, g = lane >> 4;
  const int q0 = blockIdx.x * 32, b = blockIdx.y;
  const int hg = blockIdx.z & 1, sp = blockIdx.z >> 1;
  const int h = hg * 4 + w;
  const size_t bh = (size_t)(b * 8 + h);
  const int kvbase = sp * 512;

  // Q fragments (B-operand; col = q)
  short8 qf[2];
#pragma unroll
  for (int qs = 0; qs < 2; ++qs)
    qf[qs] = ld8(qb + (bh * 1024 + q0 + qs * 16 + c) * 32 + g * 8);

  f32x4 oacc[2][2] = {};
  float mold[2] = {-1e30f, -1e30f};
  float lrow[2] = {0.f, 0.f};

  // cooperative bias staging indices: 256 thr x 16B covers [32 q][64 kv] f16
  const int sqr = tid >> 3, skv = (tid & 7) * 8;
  const _Float16* bg = bias16 + ((size_t)(b * 1024 + q0 + sqr)) * 1024;
  *reinterpret_cast<uint4_t*>(&bias_lds[0][sqr][skv]) =
      *reinterpret_cast<const uint4_t*>(bg + kvbase + skv);
  __syncthreads();

  for (int t8 = 0; t8 < 8; ++t8) {
    const int buf = t8 & 1;
    const int kv0 = kvbase + t8 * 64;
    uint4_t vpre;
    if (t8 < 7) vpre = *reinterpret_cast<const uint4_t*>(bg + kv0 + 64 + skv);

    // K fragments (A-operand; row = kv)
    short8 kf[4];
#pragma unroll
    for (int t = 0; t < 4; ++t)
      kf[t] = ld8(kb + (bh * 1024 + kv0 + t * 16 + c) * 32 + g * 8);

#pragma unroll
    for (int qs = 0; qs < 2; ++qs) {
      f32x4 z = {};
      f32x4 s[4];
#pragma unroll
      for (int t = 0; t < 4; ++t) s[t] = mfma16(kf[t], qf[qs], z);
      // lane holds S[q=q0+qs*16+c][kv0 + 16t + 4g + r]
      float p[4][4];
      float m16 = -1e30f;
#pragma unroll
      for (int t = 0; t < 4; ++t) {
        f16x4 bv = *reinterpret_cast<const f16x4*>(&bias_lds[buf][qs * 16 + c][t * 16 + 4 * g]);
#pragma unroll
        for (int r = 0; r < 4; ++r) {
          float sv = s[t][r] + (float)bv[r];
          p[t][r] = sv;
          m16 = fmaxf(m16, sv);
        }
      }
      m16 = fmaxf(m16, __shfl_xor(m16, 16));
      m16 = fmaxf(m16, __shfl_xor(m16, 32));
      float mn = fmaxf(mold[qs], m16);
      float corr = __expf(mold[qs] - mn);
      mold[qs] = mn;
      float ps = 0.f;
#pragma unroll
      for (int t = 0; t < 4; ++t)
#pragma unroll
        for (int r = 0; r < 4; ++r) {
          float e = __expf(p[t][r] - mn);
          p[t][r] = e;
          ps += e;
        }
      ps += __shfl_xor(ps, 16);
      ps += __shfl_xor(ps, 32);
      lrow[qs] = lrow[qs] * corr + ps;
#pragma unroll
      for (int hs = 0; hs < 2; ++hs) oacc[qs][hs] *= corr;
      // pack P -> bf16 pairs, write b64 (kv idx 16t+4g+{0..3})
#pragma unroll
      for (int t = 0; t < 4; ++t) {
        uint2_t pk;
        pk[0] = (unsigned)f2bf(p[t][0]) | ((unsigned)f2bf(p[t][1]) << 16);
        pk[1] = (unsigned)f2bf(p[t][2]) | ((unsigned)f2bf(p[t][3]) << 16);
        *reinterpret_cast<uint2_t*>(&p_lds[w][qs * 16 + c][t * 16 + 4 * g]) = pk;
      }
    }

    // O^T += V^T * P^T : A = vT rows (d), B = P rows (q), k = kv
#pragma unroll
    for (int t2 = 0; t2 < 2; ++t2) {
      short8 pf[2];
#pragma unroll
      for (int qs = 0; qs < 2; ++qs)
        pf[qs] = ld8(&p_lds[w][qs * 16 + c][t2 * 32 + g * 8]);
#pragma unroll
      for (int hs = 0; hs < 2; ++hs) {
        short8 vf = ld8(vT + (bh * 32 + hs * 16 + c) * 1024 + kv0 + t2 * 32 + g * 8);
#pragma unroll
        for (int qs = 0; qs < 2; ++qs)
          oacc[qs][hs] = mfma16(vf, pf[qs], oacc[qs][hs]);
      }
    }

    if (t8 < 7) *reinterpret_cast<uint4_t*>(&bias_lds[buf ^ 1][sqr][skv]) = vpre;
    __syncthreads();
  }

  // epilogue: store unnormalized O^T (lane holds O[q=qs*16+c][d=hs*16+4g+r]) + (m,l)
#pragma unroll
  for (int qs = 0; qs < 2; ++qs) {
    size_t qrow = ((size_t)sp * 64 + bh) * 1024 + q0 + qs * 16 + c;
#pragma unroll
    for (int hs = 0; hs < 2; ++hs)
      *reinterpret_cast<f32x4*>(o_part + qrow * 32 + hs * 16 + 4 * g) = oacc[qs][hs];
    if (g == 0) {
      float2_t ml = {mold[qs], lrow[qs]};
      *reinterpret_cast<float2_t*>(ml_part + qrow * 2) = ml;
    }
  }
}

// ---------------- combine kv-splits ----------------
__global__ __launch_bounds__(256) void k_combine(const float* __restrict__ o_part,
                                                 const float* __restrict__ ml_part,
                                                 float* __restrict__ ao) {
  const int id = blockIdx.x * 256 + threadIdx.x;  // [0, 524288)
  const int d4 = id & 7;
  const int q = (id >> 3) & 1023;
  const int bh = id >> 13;  // [0,64)
  const size_t r0 = ((size_t)bh * 1024 + q);
  const size_t r1 = ((size_t)64 * 1024) + r0;
  f32x4 o0 = *reinterpret_cast<const f32x4*>(o_part + r0 * 32 + d4 * 4);
  f32x4 o1 = *reinterpret_cast<const f32x4*>(o_part + r1 * 32 + d4 * 4);
  float m0 = ml_part[r0 * 2], l0 = ml_part[r0 * 2 + 1];
  float m1 = ml_part[r1 * 2], l1 = ml_part[r1 * 2 + 1];
  float mm = fmaxf(m0, m1);
  float a0 = __expf(m0 - mm), a1 = __expf(m1 - mm);
  float inv = 1.0f / (a0 * l0 + a1 * l1);
  f32x4 res = (o0 * a0 + o1 * a1) * inv;
  int b = bh >> 3, h = bh & 7;
  *reinterpret_cast<f32x4*>(ao + ((size_t)(b * 1024 + q)) * 256 + h * 32 + d4 * 4) = res;
}

// ---------------- projection (LDS-staged A): ao[8192,256] @ wproj^T + b ----------------
__global__ __launch_bounds__(256, 4) void k_proj(const float* __restrict__ ao,
                                                 const unsigned short* __restrict__ wp_bf,
                                                 const float* __restrict__ bproj,
                                                 float* __restrict__ out) {
  __shared__ unsigned short xs[64][264];
  const int tid = threadIdx.x;
  const int w = tid >> 6, lane = tid & 63;
  const int c = lane & 15, g = lane >> 4;
  const int m0 = blockIdx.y * 64;
  const int n0 = blockIdx.x * 64;
#pragma unroll
  for (int i = 0; i < 16; ++i) {
    int idx = i * 1024 + tid * 4;
    int row = idx >> 8, col = idx & 255;
    f32x4 vv = *reinterpret_cast<const f32x4*>(ao + (size_t)(m0 + row) * 256 + col);
    ushort4_t hh;
#pragma unroll
    for (int j = 0; j < 4; ++j) hh[j] = f2bf(vv[j]);
    *reinterpret_cast<ushort4_t*>(&xs[row][col]) = hh;
  }
  __syncthreads();
  f32x4 acc[4] = {};
#pragma unroll
  for (int k0 = 0; k0 < 256; k0 += 32) {
    short8 af = ld8(&xs[w * 16 + c][k0 + g * 8]);
#pragma unroll
    for (int nb = 0; nb < 4; ++nb) {
      short8 bf = ld8(wp_bf + (size_t)(n0 + nb * 16 + c) * 256 + k0 + g * 8);
      acc[nb] = mfma16(af, bf, acc[nb]);
    }
  }
#pragma unroll
  for (int nb = 0; nb < 4; ++nb) {
    int col = n0 + nb * 16 + c;
    float bv = bproj[col];
#pragma unroll
    for (int r = 0; r < 4; ++r) {
      int row = m0 + w * 16 + g * 4 + r;
      out[(size_t)row * 256 + col] = acc[nb][r] + bv;
    }
  }
}

extern "C" void kernel_launch(void* const* d_in, const int* in_sizes, int n_in,
                              void* d_out, int out_size, void* d_ws, size_t ws_size,
                              hipStream_t stream) {
  const float* x = (const float*)d_in[0];
  const float* elev = (const float*)d_in[1];
  const float* uw = (const float*)d_in[2];
  const float* vw = (const float*)d_in[3];
  const float* wqkv = (const float*)d_in[4];
  const float* wproj = (const float*)d_in[5];
  const float* bproj = (const float*)d_in[6];
  const float* alpha = (const float*)d_in[7];
  const float* beta = (const float*)d_in[8];
  float* out = (float*)d_out;

  char* p = (char*)d_ws;
  auto alloc = [&](size_t bytes) {
    char* r = p;
    p += (bytes + 255) & ~(size_t)255;
    return r;
  };
  float* ws_wind = (float*)alloc(8192 * 4);
  unsigned short* wqkv_bf = (unsigned short*)alloc((size_t)768 * 256 * 2);
  unsigned short* wproj_bf = (unsigned short*)alloc((size_t)256 * 256 * 2);
  unsigned short* qb = (unsigned short*)alloc((size_t)2097152 * 2);
  unsigned short* kb = (unsigned short*)alloc((size_t)2097152 * 2);
  unsigned short* vb = (unsigned short*)alloc((size_t)2097152 * 2);
  unsigned short* vT = (unsigned short*)alloc((size_t)2097152 * 2);
  _Float16* bias16 = (_Float16*)alloc((size_t)8 * 1024 * 1024 * 2);
  float* o_part = (float*)alloc((size_t)2 * 2097152 * 4);
  float* ml_part = (float*)alloc((size_t)2 * 65536 * 2 * 4);
  float* ao = (float*)alloc((size_t)2097152 * 4);

  k_prep<<<dim3(1056), dim3(256), 0, stream>>>(wqkv, wproj, uw, vw, wqkv_bf, wproj_bf, ws_wind);
  k_bias<<<dim3(1024, 8), dim3(256), 0, stream>>>(elev, ws_wind, alpha, beta, bias16);
  k_qkv<<<dim3(12, 128), dim3(256), 0, stream>>>(x, wqkv_bf, qb, kb, vb);
  k_vtrans<<<dim3(16, 64), dim3(256), 0, stream>>>(vb, vT);
  k_attn<<<dim3(32, 8, 4), dim3(256), 0, stream>>>(qb, kb, vT, bias16, o_part, ml_part);
  k_combine<<<dim3(2048), dim3(256), 0, stream>>>(o_part, ml_part, ao);
  k_proj<<<dim3(4, 128), dim3(256), 0, stream>>>(ao, wproj_bf, bproj, out);
}

// Round 3
// 162.804 us; speedup vs baseline: 1.3282x; 1.0391x over previous
//
#include <hip/hip_runtime.h>
#include <stdint.h>

typedef __attribute__((ext_vector_type(8))) short short8;
typedef __attribute__((ext_vector_type(8))) __bf16 bf16x8;
typedef __attribute__((ext_vector_type(4))) float f32x4;
typedef __attribute__((ext_vector_type(4))) _Float16 f16x4;
typedef __attribute__((ext_vector_type(4))) unsigned short ushort4_t;
typedef __attribute__((ext_vector_type(2))) unsigned int uint2_t;
typedef __attribute__((ext_vector_type(2))) float float2_t;

__device__ __forceinline__ unsigned short f2bf(float f) {
  unsigned int u = __builtin_bit_cast(unsigned int, f);
  u += 0x7fffu + ((u >> 16) & 1u);
  return (unsigned short)(u >> 16);
}

__device__ __forceinline__ f32x4 mfma16(short8 a, short8 b, f32x4 c) {
  return __builtin_amdgcn_mfma_f32_16x16x32_bf16(
      __builtin_bit_cast(bf16x8, a), __builtin_bit_cast(bf16x8, b), c, 0, 0, 0);
}

__device__ __forceinline__ short8 ld8(const unsigned short* p) {
  return *reinterpret_cast<const short8*>(p);
}

// ---------------- prep: weight cvt + wind strength ----------------
__global__ __launch_bounds__(256) void k_prep(const float* __restrict__ wqkv,
                                              const float* __restrict__ wproj,
                                              const float* __restrict__ u,
                                              const float* __restrict__ v,
                                              unsigned short* __restrict__ wqkv_bf,
                                              unsigned short* __restrict__ wproj_bf,
                                              float* __restrict__ ws) {
  int gx = blockIdx.x, t = threadIdx.x;
  if (gx < 768) {
    int i = gx * 256 + t;
    wqkv_bf[i] = f2bf(wqkv[i]);
  } else if (gx < 1024) {
    int i = (gx - 768) * 256 + t;
    wproj_bf[i] = f2bf(wproj[i]);
  } else {
    int i = (gx - 1024) * 256 + t;  // [0, 8192)
    int b = i >> 10, n = i & 1023;
    int ph = n >> 5, pw = n & 31;
    const float* ub = u + b * 4096;
    const float* vb = v + b * 4096;
    float s = 0.f;
#pragma unroll
    for (int dy = 0; dy < 2; ++dy)
#pragma unroll
      for (int dx = 0; dx < 2; ++dx) {
        int idx = (2 * ph + dy) * 64 + (2 * pw + dx);
        float uu = ub[idx], vv = vb[idx];
        s += sqrtf(uu * uu + vv * vv + 1e-8f);
      }
    ws[i] = s * 0.25f;
  }
}

// ---------------- QKV GEMM (LDS-staged A, n-tile 192, v written transposed) ----
__global__ __launch_bounds__(256, 4) void k_qkv(const float* __restrict__ x,
                                                const unsigned short* __restrict__ wq_bf,
                                                unsigned short* __restrict__ qb,
                                                unsigned short* __restrict__ kb,
                                                unsigned short* __restrict__ vT) {
  __shared__ unsigned short xs[64][264];
  const int tid = threadIdx.x;
  const int w = tid >> 6, lane = tid & 63;
  const int c = lane & 15, g = lane >> 4;
  const int m0 = blockIdx.y * 64;
  const int n0 = blockIdx.x * 192;
  // cooperative coalesced load + convert
#pragma unroll
  for (int i = 0; i < 16; ++i) {
    int idx = i * 1024 + tid * 4;
    int row = idx >> 8, col = idx & 255;
    f32x4 vv = *reinterpret_cast<const f32x4*>(x + (size_t)(m0 + row) * 256 + col);
    ushort4_t hh;
#pragma unroll
    for (int j = 0; j < 4; ++j) hh[j] = f2bf(vv[j]);
    *reinterpret_cast<ushort4_t*>(&xs[row][col]) = hh;
  }
  __syncthreads();
  f32x4 acc[12] = {};
#pragma unroll
  for (int k0 = 0; k0 < 256; k0 += 32) {
    short8 af = ld8(&xs[w * 16 + c][k0 + g * 8]);
#pragma unroll
    for (int nb = 0; nb < 12; ++nb) {
      short8 bf = ld8(wq_bf + (size_t)(n0 + nb * 16 + c) * 256 + k0 + g * 8);
      acc[nb] = mfma16(af, bf, acc[nb]);
    }
  }
#pragma unroll
  for (int nb = 0; nb < 12; ++nb) {
    int col = n0 + nb * 16 + c;  // [0,768)
    int s = col >> 8, rem = col & 255;
    int h = rem >> 5, d = rem & 31;
    int nrow0 = m0 + w * 16 + g * 4;  // [0,8192), 4 consecutive rows
    int b = nrow0 >> 10, nn = nrow0 & 1023;
    size_t bh = (size_t)(b * 8 + h);
    if (s == 2) {
      // v: write directly in transposed layout vT[bh*32+d][n]
      ushort4_t pk;
#pragma unroll
      for (int r = 0; r < 4; ++r) pk[r] = f2bf(acc[nb][r]);
      *reinterpret_cast<ushort4_t*>(vT + (bh * 32 + d) * 1024 + nn) = pk;
    } else {
      unsigned short* dst = (s == 0) ? qb : kb;
      float scale = (s == 0) ? 0.17677669529663687f : 1.0f;  // hd^-0.5 folded into q
#pragma unroll
      for (int r = 0; r < 4; ++r)
        dst[(bh * 1024 + nn + r) * 32 + d] = f2bf(acc[nb][r] * scale);
    }
  }
}

// ---------------- fused attention, swapped-QK^T, kv-split, in-kernel bias ----
// grid: (32 qtiles, 8 b, 4 = hg + 2*sp); block 256 = 4 waves; wave = head hg*4+w
__global__ __launch_bounds__(256, 4) void k_attn(const unsigned short* __restrict__ qb,
                                                 const unsigned short* __restrict__ kb,
                                                 const unsigned short* __restrict__ vT,
                                                 const float* __restrict__ elev,
                                                 const float* __restrict__ wsd,
                                                 const float* __restrict__ alphap,
                                                 const float* __restrict__ betap,
                                                 float* __restrict__ o_part,
                                                 float* __restrict__ ml_part) {
  __shared__ _Float16 bias_lds[2][32][72];
  __shared__ unsigned short p_lds[4][32][72];
  const int tid = threadIdx.x;
  const int w = tid >> 6, lane = tid & 63;
  const int c = lane & 15, g = lane >> 4;
  const int q0 = blockIdx.x * 32, b = blockIdx.y;
  const int hg = blockIdx.z & 1, sp = blockIdx.z >> 1;
  const int h = hg * 4 + w;
  const size_t bh = (size_t)(b * 8 + h);
  const int kvbase = sp * 512;
  const float alpha = alphap[0], beta = betap[0];

  // bias staging: thread t covers (q=sqr, kv=skv..skv+7)
  const int sqr = tid >> 3, skv = (tid & 7) * 8;
  const float* eb = elev + b * 1024;
  const float* wb = wsd + b * 1024;
  const float ei = eb[q0 + sqr], wi = wb[q0 + sqr];

  auto stage_bias = [&](int buf, int kv0) {
    f32x4 ej0 = *reinterpret_cast<const f32x4*>(eb + kv0 + skv);
    f32x4 ej1 = *reinterpret_cast<const f32x4*>(eb + kv0 + skv + 4);
    f32x4 wj0 = *reinterpret_cast<const f32x4*>(wb + kv0 + skv);
    f32x4 wj1 = *reinterpret_cast<const f32x4*>(wb + kv0 + skv + 4);
    f16x4 h0, h1;
#pragma unroll
    for (int j = 0; j < 4; ++j) {
      float dd = fmaxf((ej0[j] - ei) * 1e-3f, 0.f);
      float sig = 1.0f / (1.0f + __expf(5.0f - (wi + wj0[j]) * 0.5f));
      h0[j] = (_Float16)fminf(fmaxf(-alpha * dd * (1.0f - beta * sig), -10.0f), 0.0f);
      float dd1 = fmaxf((ej1[j] - ei) * 1e-3f, 0.f);
      float sig1 = 1.0f / (1.0f + __expf(5.0f - (wi + wj1[j]) * 0.5f));
      h1[j] = (_Float16)fminf(fmaxf(-alpha * dd1 * (1.0f - beta * sig1), -10.0f), 0.0f);
    }
    *reinterpret_cast<f16x4*>(&bias_lds[buf][sqr][skv]) = h0;
    *reinterpret_cast<f16x4*>(&bias_lds[buf][sqr][skv + 4]) = h1;
  };

  stage_bias(0, kvbase);

  // Q fragments (B-operand; col = q)
  short8 qf[2];
#pragma unroll
  for (int qs = 0; qs < 2; ++qs)
    qf[qs] = ld8(qb + (bh * 1024 + q0 + qs * 16 + c) * 32 + g * 8);

  f32x4 oacc[2][2] = {};
  float mold[2] = {-1e30f, -1e30f};
  float lrow[2] = {0.f, 0.f};
  __syncthreads();

  for (int t8 = 0; t8 < 8; ++t8) {
    const int buf = t8 & 1;
    const int kv0 = kvbase + t8 * 64;

    // K fragments (A-operand; row = kv)
    short8 kf[4];
#pragma unroll
    for (int t = 0; t < 4; ++t)
      kf[t] = ld8(kb + (bh * 1024 + kv0 + t * 16 + c) * 32 + g * 8);

#pragma unroll
    for (int qs = 0; qs < 2; ++qs) {
      f32x4 z = {};
      f32x4 s[4];
#pragma unroll
      for (int t = 0; t < 4; ++t) s[t] = mfma16(kf[t], qf[qs], z);
      // lane holds S[q=q0+qs*16+c][kv0 + 16t + 4g + r]
      float p[4][4];
      float m16 = -1e30f;
#pragma unroll
      for (int t = 0; t < 4; ++t) {
        f16x4 bv = *reinterpret_cast<const f16x4*>(&bias_lds[buf][qs * 16 + c][t * 16 + 4 * g]);
#pragma unroll
        for (int r = 0; r < 4; ++r) {
          float sv = s[t][r] + (float)bv[r];
          p[t][r] = sv;
          m16 = fmaxf(m16, sv);
        }
      }
      m16 = fmaxf(m16, __shfl_xor(m16, 16));
      m16 = fmaxf(m16, __shfl_xor(m16, 32));
      float mn = fmaxf(mold[qs], m16);
      float corr = __expf(mold[qs] - mn);
      mold[qs] = mn;
      float ps = 0.f;
#pragma unroll
      for (int t = 0; t < 4; ++t)
#pragma unroll
        for (int r = 0; r < 4; ++r) {
          float e = __expf(p[t][r] - mn);
          p[t][r] = e;
          ps += e;
        }
      ps += __shfl_xor(ps, 16);
      ps += __shfl_xor(ps, 32);
      lrow[qs] = lrow[qs] * corr + ps;
#pragma unroll
      for (int hs = 0; hs < 2; ++hs) oacc[qs][hs] *= corr;
      // pack P -> bf16 pairs, write b64 (kv idx 16t+4g+{0..3})
#pragma unroll
      for (int t = 0; t < 4; ++t) {
        uint2_t pk;
        pk[0] = (unsigned)f2bf(p[t][0]) | ((unsigned)f2bf(p[t][1]) << 16);
        pk[1] = (unsigned)f2bf(p[t][2]) | ((unsigned)f2bf(p[t][3]) << 16);
        *reinterpret_cast<uint2_t*>(&p_lds[w][qs * 16 + c][t * 16 + 4 * g]) = pk;
      }
    }

    // O^T += V^T * P^T : A = vT rows (d), B = P rows (q), k = kv
#pragma unroll
    for (int t2 = 0; t2 < 2; ++t2) {
      short8 pf[2];
#pragma unroll
      for (int qs = 0; qs < 2; ++qs)
        pf[qs] = ld8(&p_lds[w][qs * 16 + c][t2 * 32 + g * 8]);
#pragma unroll
      for (int hs = 0; hs < 2; ++hs) {
        short8 vf = ld8(vT + (bh * 32 + hs * 16 + c) * 1024 + kv0 + t2 * 32 + g * 8);
#pragma unroll
        for (int qs = 0; qs < 2; ++qs)
          oacc[qs][hs] = mfma16(vf, pf[qs], oacc[qs][hs]);
      }
    }

    if (t8 < 7) stage_bias(buf ^ 1, kv0 + 64);
    __syncthreads();
  }

  // epilogue: store unnormalized O^T (lane holds O[q=qs*16+c][d=hs*16+4g+r]) + (m,l)
#pragma unroll
  for (int qs = 0; qs < 2; ++qs) {
    size_t qrow = ((size_t)sp * 64 + bh) * 1024 + q0 + qs * 16 + c;
#pragma unroll
    for (int hs = 0; hs < 2; ++hs)
      *reinterpret_cast<f32x4*>(o_part + qrow * 32 + hs * 16 + 4 * g) = oacc[qs][hs];
    if (g == 0) {
      float2_t ml = {mold[qs], lrow[qs]};
      *reinterpret_cast<float2_t*>(ml_part + qrow * 2) = ml;
    }
  }
}

// ---------------- projection fused with kv-split combine ----------------
// grid: 256 blocks, each 32 output rows x 256 cols; 4 waves (wm = w&1, wn = w>>1)
__global__ __launch_bounds__(256, 2) void k_proj(const float* __restrict__ o_part,
                                                 const float* __restrict__ ml_part,
                                                 const unsigned short* __restrict__ wp_bf,
                                                 const float* __restrict__ bproj,
                                                 float* __restrict__ out) {
  __shared__ unsigned short xs[32][264];
  const int tid = threadIdx.x;
  const int w = tid >> 6, lane = tid & 63;
  const int c = lane & 15, g = lane >> 4;
  const int wm = w & 1, wn = w >> 1;
  const int m0 = blockIdx.x * 32;
  const int b = m0 >> 10, q0 = m0 & 1023;

  // staging: combine sp halves -> bf16 into xs[32][256]
  const int qq = tid >> 3, d0 = (tid & 7) * 4;
#pragma unroll
  for (int h = 0; h < 8; ++h) {
    size_t r0 = ((size_t)(b * 8 + h) * 1024 + q0 + qq);
    size_t r1 = r0 + (size_t)64 * 1024;
    f32x4 o0 = *reinterpret_cast<const f32x4*>(o_part + r0 * 32 + d0);
    f32x4 o1 = *reinterpret_cast<const f32x4*>(o_part + r1 * 32 + d0);
    float2_t ml0 = *reinterpret_cast<const float2_t*>(ml_part + r0 * 2);
    float2_t ml1 = *reinterpret_cast<const float2_t*>(ml_part + r1 * 2);
    float mm = fmaxf(ml0[0], ml1[0]);
    float a0 = __expf(ml0[0] - mm), a1 = __expf(ml1[0] - mm);
    float inv = 1.0f / (a0 * ml0[1] + a1 * ml1[1]);
    ushort4_t hh;
#pragma unroll
    for (int j = 0; j < 4; ++j) hh[j] = f2bf((o0[j] * a0 + o1[j] * a1) * inv);
    *reinterpret_cast<ushort4_t*>(&xs[qq][h * 32 + d0]) = hh;
  }
  __syncthreads();

  f32x4 acc[8] = {};
#pragma unroll
  for (int k0 = 0; k0 < 256; k0 += 32) {
    short8 af = ld8(&xs[wm * 16 + c][k0 + g * 8]);
#pragma unroll
    for (int nb = 0; nb < 8; ++nb) {
      short8 bf = ld8(wp_bf + (size_t)(wn * 128 + nb * 16 + c) * 256 + k0 + g * 8);
      acc[nb] = mfma16(af, bf, acc[nb]);
    }
  }
#pragma unroll
  for (int nb = 0; nb < 8; ++nb) {
    int col = wn * 128 + nb * 16 + c;
    float bv = bproj[col];
#pragma unroll
    for (int r = 0; r < 4; ++r) {
      int row = m0 + wm * 16 + g * 4 + r;
      out[(size_t)row * 256 + col] = acc[nb][r] + bv;
    }
  }
}

extern "C" void kernel_launch(void* const* d_in, const int* in_sizes, int n_in,
                              void* d_out, int out_size, void* d_ws, size_t ws_size,
                              hipStream_t stream) {
  const float* x = (const float*)d_in[0];
  const float* elev = (const float*)d_in[1];
  const float* uw = (const float*)d_in[2];
  const float* vw = (const float*)d_in[3];
  const float* wqkv = (const float*)d_in[4];
  const float* wproj = (const float*)d_in[5];
  const float* bproj = (const float*)d_in[6];
  const float* alpha = (const float*)d_in[7];
  const float* beta = (const float*)d_in[8];
  float* out = (float*)d_out;

  char* p = (char*)d_ws;
  auto alloc = [&](size_t bytes) {
    char* r = p;
    p += (bytes + 255) & ~(size_t)255;
    return r;
  };
  float* ws_wind = (float*)alloc(8192 * 4);
  unsigned short* wqkv_bf = (unsigned short*)alloc((size_t)768 * 256 * 2);
  unsigned short* wproj_bf = (unsigned short*)alloc((size_t)256 * 256 * 2);
  unsigned short* qb = (unsigned short*)alloc((size_t)2097152 * 2);
  unsigned short* kb = (unsigned short*)alloc((size_t)2097152 * 2);
  unsigned short* vT = (unsigned short*)alloc((size_t)2097152 * 2);
  float* o_part = (float*)alloc((size_t)2 * 2097152 * 4);
  float* ml_part = (float*)alloc((size_t)2 * 65536 * 2 * 4);

  k_prep<<<dim3(1056), dim3(256), 0, stream>>>(wqkv, wproj, uw, vw, wqkv_bf, wproj_bf, ws_wind);
  k_qkv<<<dim3(4, 128), dim3(256), 0, stream>>>(x, wqkv_bf, qb, kb, vT);
  k_attn<<<dim3(32, 8, 4), dim3(256), 0, stream>>>(qb, kb, vT, elev, ws_wind, alpha, beta, o_part, ml_part);
  k_proj<<<dim3(256), dim3(256), 0, stream>>>(o_part, ml_part, wproj_bf, bproj, out);
}